// Round 5
// baseline (15075.810 us; speedup 1.0000x reference)
//
#include <hip/hip_runtime.h>
#include <hip/hip_bf16.h>
#include <stdint.h>

// Problem sizes (fixed)
#define NB 512     // batch
#define NS 256     // source length
#define ND 256     // hidden dim
#define NT 256     // decode steps
#define NO 3       // output dim
#define KG 544     // padded gate K: [ctx 0..255 | xin 256..258 | pad..287 | h 288..543]
#define PROW 552   // panel row stride (shorts), padded for LDS banks

#define LOG2E 1.44269504088896340736f
#define C2 (2.0f*LOG2E)

typedef short short8v __attribute__((ext_vector_type(8)));
typedef float f32x4   __attribute__((ext_vector_type(4)));

#if __has_builtin(__builtin_amdgcn_exp2f)
__device__ __forceinline__ float exp2_fast(float x){ return __builtin_amdgcn_exp2f(x); }
#else
__device__ __forceinline__ float exp2_fast(float x){ return exp2f(x); }
#endif
#if __has_builtin(__builtin_amdgcn_rcpf)
__device__ __forceinline__ float rcp_fast(float x){ return __builtin_amdgcn_rcpf(x); }
#else
__device__ __forceinline__ float rcp_fast(float x){ return 1.0f/x; }
#endif

__device__ __forceinline__ float tanh_f(float x){
  float e = exp2_fast(x * C2);
  return 1.0f - 2.0f*rcp_fast(e + 1.0f);
}
__device__ __forceinline__ float sigm_f(float x){
  return rcp_fast(1.0f + exp2_fast(-x*LOG2E));
}
__device__ __forceinline__ float bflo(uint32_t u){ return __uint_as_float(u<<16); }
__device__ __forceinline__ float bfhi(uint32_t u){ return __uint_as_float(u & 0xffff0000u); }
__device__ __forceinline__ uint16_t f2bf(float f){   // round-to-nearest-even bf16
  uint32_t u = __float_as_uint(f);
  return (uint16_t)((u + 0x7fffu + ((u>>16)&1u)) >> 16);
}
__device__ __forceinline__ uint32_t pack2(float a, float b){
  return (uint32_t)f2bf(a) | ((uint32_t)f2bf(b) << 16);
}

#if __has_builtin(__builtin_amdgcn_fdot2_f32_bf16)
typedef __bf16 bfp2 __attribute__((ext_vector_type(2)));
__device__ __forceinline__ float dot2bf(uint32_t a, uint32_t b, float c){
  return __builtin_amdgcn_fdot2_f32_bf16(__builtin_bit_cast(bfp2, a),
                                         __builtin_bit_cast(bfp2, b), c, false);
}
#else
__device__ __forceinline__ float dot2bf(uint32_t a, uint32_t b, float c){
  return c + bflo(a)*bflo(b) + bfhi(a)*bfhi(b);
}
#endif

__device__ __forceinline__ f32x4 mfma_bf16(short8v a, short8v b, f32x4 c){
  return __builtin_amdgcn_mfma_f32_16x16x32_bf16(a, b, c, 0, 0, 0);
}

// ---------------- prep kernels ----------------

__global__ void k_transpose(const float* __restrict__ src, float* __restrict__ dst,
                            int R, int C){
  int idx = blockIdx.x*256 + threadIdx.x;
  if (idx < R*C){
    int r = idx / C, c = idx - r*C;
    dst[c*R + r] = src[idx];
  }
}

// UK8[b][e8][s][8] (bf16, d-interleaved-by-8, PRE-SCALED by 2*log2e)
__global__ void __launch_bounds__(256) k_uk(const float* __restrict__ e_all,
    const float* __restrict__ UaT, const float* __restrict__ bu,
    uint16_t* __restrict__ UK){
  __shared__ float At[ND][20];
  const int t = threadIdx.x;
  const int m0 = blockIdx.x * 16;
  const int b  = m0 >> 8;
  const int s0 = m0 & (NS-1);
  #pragma unroll
  for (int i=0;i<16;i++)
    At[t][i] = e_all[(size_t)(m0+i)*ND + t];
  __syncthreads();
  float acc[16];
  float bue = bu[t];
  #pragma unroll
  for (int i=0;i<16;i++) acc[i] = bue;
  for (int d=0; d<ND; ++d){
    float u = UaT[d*ND + t];
    const float4 a0 = *(const float4*)&At[d][0];
    const float4 a1 = *(const float4*)&At[d][4];
    const float4 a2 = *(const float4*)&At[d][8];
    const float4 a3 = *(const float4*)&At[d][12];
    acc[0]+=a0.x*u;  acc[1]+=a0.y*u;  acc[2]+=a0.z*u;  acc[3]+=a0.w*u;
    acc[4]+=a1.x*u;  acc[5]+=a1.y*u;  acc[6]+=a1.z*u;  acc[7]+=a1.w*u;
    acc[8]+=a2.x*u;  acc[9]+=a2.y*u;  acc[10]+=a2.z*u; acc[11]+=a2.w*u;
    acc[12]+=a3.x*u; acc[13]+=a3.y*u; acc[14]+=a3.z*u; acc[15]+=a3.w*u;
  }
  const int e8 = t>>3, j = t&7;
  uint16_t* base = UK + (size_t)b*NS*ND + (size_t)e8*(NS*8) + j;
  #pragma unroll
  for (int i=0;i<16;i++)
    base[(size_t)(s0+i)*8] = f2bf(acc[i] * C2);
}

// EP[b][s2][d] = {bf16 e[b][2s2][d], bf16 e[b][2s2+1][d]}
__global__ void k_ep(const float* __restrict__ e_all, uint32_t* __restrict__ EP){
  int idx = blockIdx.x*256 + threadIdx.x;
  if (idx >= NB*128*256) return;
  int d  = idx & 255;
  int s2 = (idx >> 8) & 127;
  int b  = idx >> 15;
  float e0 = e_all[((size_t)b*NS + 2*s2  )*ND + d];
  float e1 = e_all[((size_t)b*NS + 2*s2+1)*ND + d];
  EP[idx] = pack2(e0, e1);
}

// Wg[n][k] bf16, n in [0,768), k in [0,544): k<259 -> W_ih[n][k]; 288<=k -> W_hh[n][k-288]; else 0
__global__ void k_wg(const float* __restrict__ W_ih, const float* __restrict__ W_hh,
                     uint16_t* __restrict__ Wg){
  int idx = blockIdx.x*256 + threadIdx.x;
  if (idx >= 768*KG) return;
  int n = idx / KG, k = idx - n*KG;
  float v = 0.f;
  if (k < 259)       v = W_ih[(size_t)n*259 + k];
  else if (k >= 288) v = W_hh[(size_t)n*256 + (k-288)];
  Wg[idx] = f2bf(v);
}

// Wq[e][d] bf16 = Wa (row-major already [e][d])
__global__ void k_wq(const float* __restrict__ Wa, uint16_t* __restrict__ Wq){
  int idx = blockIdx.x*256 + threadIdx.x;
  if (idx >= ND*ND) return;
  Wq[idx] = f2bf(Wa[idx]);
}

// ---------------- persistent decode kernel ----------------
// 256 blocks x 1024 threads; TWO batch elements per block.
// Q and G matvecs on MFMA (M=2 in A-rows 0..1); S on VALU; C on dot2.
__global__ void __launch_bounds__(1024, 4) k_decode(
    const uint16_t* __restrict__ UK, const uint32_t* __restrict__ EP,
    const uint16_t* __restrict__ Wg, const uint16_t* __restrict__ Wq,
    const float* __restrict__ e_last,
    const float* __restrict__ Va, const float* __restrict__ bv,
    const float* __restrict__ b_ih, const float* __restrict__ b_hh,
    const float* __restrict__ ba, const float* __restrict__ bo,
    const float* __restrict__ Wo,
    float* __restrict__ dout, float* __restrict__ hT_out, float* __restrict__ ca)
{
  __shared__ __align__(16) uint16_t panelA[16*PROW]; // A-panel: rows=batch (2 live), cols=k
  __shared__ float    hf[2][ND];                     // h in f32 (recurrence precision)
  __shared__ float    xin[2][4];
  __shared__ __align__(16) float qL[2][ND];          // pre-scaled q
  __shared__ __align__(16) float va2[ND];            // 2*Va
  __shared__ float    WoL[3*ND];
  __shared__ float    spart[2][2][ND];
  __shared__ __align__(16) float cpart[2][8][ND];
  __shared__ uint32_t wb[2][128];
  __shared__ float    red[16];

  const int t    = threadIdx.x;
  const int d    = t & 255;
  const int q4   = t >> 8;
  const int bi   = q4 >> 1;
  const int half = q4 & 1;
  const int lane = t & 63;
  const int w    = t >> 6;
  const int b0   = blockIdx.x * 2;

  // ---- init ----
  for (int i=t; i<16*PROW; i+=1024) panelA[i] = 0;
  if (q4 == 0){
    va2[d] = 2.0f*Va[d];
    WoL[d] = Wo[d]; WoL[256+d] = Wo[256+d]; WoL[512+d] = Wo[512+d];
    if (d < 4){ xin[0][d]=0.f; xin[1][d]=0.f; }
  }
  if (q4 < 2) hf[q4][d] = e_last[(size_t)(b0+q4)*ND + d];
  // per-thread epilogue constants (col ncol = w*16 + lane&15; used by lane<16)
  const int ncol = (w<<4) + (lane & 15);
  const float biasR  = b_ih[ncol]     + b_hh[ncol];
  const float biasZ  = b_ih[256+ncol] + b_hh[256+ncol];
  const float biasNi = b_ih[512+ncol];
  const float biasNh = b_hh[512+ncol];
  const float baq    = ba[ncol];
  const float bv0 = bv[0];
  const float bo0 = bo[0], bo1 = bo[1], bo2 = bo[2];
  __syncthreads();                       // panel zeroed, va2/hf ready
  if (q4 < 2) panelA[q4*PROW + 288 + d] = f2bf(hf[q4][d]);
  float sumVaH = 0.f;
  {
    #pragma unroll 8
    for (int e = half*128; e < half*128+128; ++e) sumVaH += va2[e];
    sumVaH *= 0.5f;
  }
  __syncthreads();                       // h-panel visible

  const uint16_t* ukb  = UK + (size_t)(b0+bi)*NS*ND + (size_t)half*16*2048 + (size_t)d*8;
  const uint32_t* epbw = EP + (size_t)(b0+(w>>3))*128*256;
  float* ca_bq = ca + (size_t)(b0 + (q4&1))*(NT*NS);

  // MFMA fragment pointers (lane-dependent, step-invariant)
  const uint16_t* apG = panelA + (lane&15)*PROW + ((lane>>4)*8);        // G A-frag base
  const uint16_t* apQ = apG + 288;                                     // Q A-frag base (h)
  const uint16_t* bQ  = Wq + (size_t)(ncol)*ND + ((lane>>4)*8);        // Q B-frag: rows ncol
  const uint16_t* bR  = Wg + (size_t)(ncol)*KG + ((lane>>4)*8);
  const uint16_t* bZ  = bR + (size_t)256*KG;
  const uint16_t* bN  = bR + (size_t)512*KG;

  #pragma unroll 1
  for (int step=0; step<NT; ++step){
    // ---- Q: q = h @ Wa^T + ba via MFMA; wave w -> cols 16w..16w+15 ----
    {
      f32x4 aq = {0.f,0.f,0.f,0.f};
      #pragma unroll
      for (int ks=0; ks<8; ++ks){
        short8v av = *(const short8v*)(apQ + ks*32);
        short8v bvv= *(const short8v*)(bQ  + ks*32);
        aq = mfma_bf16(av, bvv, aq);
      }
      if (lane < 16){
        qL[0][ncol] = (aq[0] + baq) * C2;
        qL[1][ncol] = (aq[1] + baq) * C2;
      }
    }
    __syncthreads();   // B1: qL ready

    // ---- S: scores (batch bi, s=d, e-half); folded tanh on VALU ----
    {
      float acc = 0.f;
      #pragma unroll 1
      for (int g=0; g<16; g+=8){
        uint4 u[8];
        #pragma unroll
        for (int j=0;j<8;j++) u[j] = *(const uint4*)(ukb + (size_t)(g+j)*2048);
        #pragma unroll
        for (int j=0;j<8;j++){
          const int e0 = half*128 + (g+j)*8;
          const float4 q0 = *(const float4*)&qL[bi][e0];
          const float4 q1 = *(const float4*)&qL[bi][e0+4];
          const float4 v0 = *(const float4*)&va2[e0];
          const float4 v1 = *(const float4*)&va2[e0+4];
          float r;
          r = rcp_fast(exp2_fast(bflo(u[j].x)+q0.x)+1.f); acc = fmaf(v0.x, r, acc);
          r = rcp_fast(exp2_fast(bfhi(u[j].x)+q0.y)+1.f); acc = fmaf(v0.y, r, acc);
          r = rcp_fast(exp2_fast(bflo(u[j].y)+q0.z)+1.f); acc = fmaf(v0.z, r, acc);
          r = rcp_fast(exp2_fast(bfhi(u[j].y)+q0.w)+1.f); acc = fmaf(v0.w, r, acc);
          r = rcp_fast(exp2_fast(bflo(u[j].z)+q1.x)+1.f); acc = fmaf(v1.x, r, acc);
          r = rcp_fast(exp2_fast(bfhi(u[j].z)+q1.y)+1.f); acc = fmaf(v1.y, r, acc);
          r = rcp_fast(exp2_fast(bflo(u[j].w)+q1.z)+1.f); acc = fmaf(v1.z, r, acc);
          r = rcp_fast(exp2_fast(bfhi(u[j].w)+q1.w)+1.f); acc = fmaf(v1.w, r, acc);
        }
      }
      spart[bi][half][d] = sumVaH - acc;
    }
    __syncthreads();   // B2

    // ---- softmax (no max-subtract; |score| <= sum|Va|+|bv| small) ----
    float p_reg = 0.f;
    if (q4 < 2){
      float sc = spart[q4][0][d] + spart[q4][1][d] + bv0;
      p_reg = exp2_fast(sc * LOG2E);
      float ssum = p_reg;
      #pragma unroll
      for (int o=32;o;o>>=1) ssum += __shfl_xor(ssum, o);
      if (lane==0) red[w] = ssum;
    }
    __syncthreads();   // B3
    if (q4 < 2){
      const int rb = q4*4;
      float ssum = (red[rb]+red[rb+1]) + (red[rb+2]+red[rb+3]);
      float wgt = p_reg * rcp_fast(ssum);
      __builtin_nontemporal_store(wgt, &ca_bq[(size_t)step*NS + d]);
      float other = __shfl_xor(wgt, 1);
      if (!(d&1)) wb[q4][d>>1] = pack2(wgt, other);
    }
    __syncthreads();   // B4: wb ready

    // ---- C: ctx via dot2 over s-pairs; wave w -> (batch w>>3, s2 range (w&7)*16) ----
    {
      const int cb = w>>3, sub = w&7;
      float c0=0,c1=0,c2=0,c3=0;
      const int s0 = sub*16;
      #pragma unroll 1
      for (int g=0; g<16; g+=8){
        uint4 ev[8]; uint32_t wp[8];
        #pragma unroll
        for (int j=0;j<8;j++){
          ev[j] = *(const uint4*)(epbw + (size_t)(s0+g+j)*256 + lane*4);
          wp[j] = wb[cb][s0+g+j];
        }
        #pragma unroll
        for (int j=0;j<8;j++){
          c0 = dot2bf(ev[j].x, wp[j], c0);
          c1 = dot2bf(ev[j].y, wp[j], c1);
          c2 = dot2bf(ev[j].z, wp[j], c2);
          c3 = dot2bf(ev[j].w, wp[j], c3);
        }
      }
      *(float4*)&cpart[cb][sub][lane*4] = make_float4(c0,c1,c2,c3);
    }
    __syncthreads();   // B5
    if (q4 < 2){
      float cx = 0.f;
      #pragma unroll
      for (int i=0;i<8;i++) cx += cpart[q4][i][d];
      panelA[q4*PROW + d] = f2bf(cx);
      if (d < 3) panelA[q4*PROW + 256 + d] = f2bf(xin[q4][d]);
    }
    __syncthreads();   // B6: panel ctx/xin ready

    // ---- G: gates via MFMA; wave w -> cols {16w, 256+16w, 512+16w} ----
    {
      f32x4 aR = {0,0,0,0}, aZ = {0,0,0,0}, aNi = {0,0,0,0}, aNh = {0,0,0,0};
      #pragma unroll
      for (int ks=0; ks<9; ++ks){          // x-part: ctx + xin (+zero pad)
        short8v av = *(const short8v*)(apG + ks*32);
        aR  = mfma_bf16(av, *(const short8v*)(bR + ks*32), aR);
        aZ  = mfma_bf16(av, *(const short8v*)(bZ + ks*32), aZ);
        aNi = mfma_bf16(av, *(const short8v*)(bN + ks*32), aNi);
      }
      #pragma unroll
      for (int ks=9; ks<17; ++ks){         // h-part
        short8v av = *(const short8v*)(apG + ks*32);
        aR  = mfma_bf16(av, *(const short8v*)(bR + ks*32), aR);
        aZ  = mfma_bf16(av, *(const short8v*)(bZ + ks*32), aZ);
        aNh = mfma_bf16(av, *(const short8v*)(bN + ks*32), aNh);
      }
      __syncthreads(); // B7: all waves done reading panel h
      if (lane < 16){
        #pragma unroll
        for (int m=0; m<2; ++m){
          float rg = sigm_f(aR[m] + biasR);
          float zg = sigm_f(aZ[m] + biasZ);
          float ng = tanh_f((aNi[m] + biasNi) + rg*(aNh[m] + biasNh));
          float hold = hf[m][ncol];
          float hnew = (1.f - zg)*ng + zg*hold;
          hf[m][ncol] = hnew;
          panelA[m*PROW + 288 + ncol] = f2bf(hnew);
        }
      }
    }
    __syncthreads();   // B8: h visible

    // ---- out projection: waves 0 (batch0) and 8 (batch1) ----
    if ((w & 7) == 0){
      const int bq = w >> 3;
      float p0=0,p1=0,p2=0;
      #pragma unroll
      for (int i=0;i<4;i++){
        float hv = hf[bq][i*64 + lane];
        p0 = fmaf(hv, WoL[      i*64+lane], p0);
        p1 = fmaf(hv, WoL[256 + i*64+lane], p1);
        p2 = fmaf(hv, WoL[512 + i*64+lane], p2);
      }
      #pragma unroll
      for (int o=32;o;o>>=1){
        p0+=__shfl_xor(p0,o); p1+=__shfl_xor(p1,o); p2+=__shfl_xor(p2,o);
      }
      if (lane==0){
        float o0=p0+bo0, o1=p1+bo1, o2=p2+bo2;
        float* do_b = dout + (size_t)(b0+bq)*(NT*NO);
        __builtin_nontemporal_store(o0, &do_b[(size_t)step*NO+0]);
        __builtin_nontemporal_store(o1, &do_b[(size_t)step*NO+1]);
        __builtin_nontemporal_store(o2, &do_b[(size_t)step*NO+2]);
        xin[bq][0]=o0; xin[bq][1]=o1; xin[bq][2]=o2;
      }
    }
    // next step's B1 orders xin/hf consumers
  }

  __syncthreads();
  if (q4 < 2) hT_out[(size_t)(b0+q4)*ND + d] = hf[q4][d];
}

// ---------------- host launch ----------------

extern "C" void kernel_launch(void* const* d_in, const int* in_sizes, int n_in,
                              void* d_out, int out_size, void* d_ws, size_t ws_size,
                              hipStream_t stream) {
  const float* e_all  = (const float*)d_in[0];
  const float* e_last = (const float*)d_in[1];
  const float* Wa     = (const float*)d_in[2];
  const float* ba     = (const float*)d_in[3];
  const float* Ua     = (const float*)d_in[4];
  const float* bu     = (const float*)d_in[5];
  const float* Va     = (const float*)d_in[6];
  const float* bv     = (const float*)d_in[7];
  const float* W_ih   = (const float*)d_in[8];
  const float* b_ih   = (const float*)d_in[9];
  const float* W_hh   = (const float*)d_in[10];
  const float* b_hh   = (const float*)d_in[11];
  const float* Wo     = (const float*)d_in[12];
  const float* bo     = (const float*)d_in[13];

  // workspace layout (~135.4 MB)
  char* ws = (char*)d_ws;
  uint16_t* UK  = (uint16_t*)(ws + 0ull);            // bf16 [B][D/8][S][8]   67108864 B
  uint32_t* EP  = (uint32_t*)(ws + 67108864ull);     // u32  [B][128][256]    67108864 B
  uint16_t* Wg  = (uint16_t*)(ws + 134217728ull);    // bf16 [768][544]         835584 B
  uint16_t* Wq  = (uint16_t*)(ws + 135053312ull);    // bf16 [256][256]         131072 B
  float*    UaT = (float*)   (ws + 135184384ull);    // f32  [256][256]         262144 B

  float* dout = (float*)d_out;                       // [B][T][3]
  float* hT   = dout + (size_t)NB*NT*NO;             // [B][D]
  float* ca   = hT   + (size_t)NB*ND;                // [B][T*S]

  // prep
  k_transpose<<<(ND*ND+255)/256,256,0,stream>>>(Ua, UaT, ND, ND);
  k_uk<<<NB*NS/16,256,0,stream>>>(e_all, UaT, bu, UK);
  k_ep<<<(NB*128*256+255)/256,256,0,stream>>>(e_all, EP);
  k_wg<<<(768*KG+255)/256,256,0,stream>>>(W_ih, W_hh, Wg);
  k_wq<<<(ND*ND+255)/256,256,0,stream>>>(Wa, Wq);

  // persistent decode: 256 blocks x 1024 threads, 2 batch elements per block
  k_decode<<<NB/2,1024,0,stream>>>(UK, EP, Wg, Wq, e_last, Va, bv,
                                   b_ih, b_hh, ba, bo, Wo, dout, hT, ca);
}